// Round 7
// baseline (639.474 us; speedup 1.0000x reference)
//
#include <hip/hip_runtime.h>

// ---------------------------------------------------------------------------
// 6-layer GCN. Layer l: y_l = b_l + D^-1/2(A+I)D^-1/2 h_l ; h_{l+1} = lrelu(y_l)@W_{l+1}
// R6: agg(+bias) fused with the NEXT layer's gemm (readlane-FMA in-wave).
//   hs_l = dinv .* h_l kept pre-scaled; y never materializes.
//   Chain: gemm0 -> F0..F3 (agg+gemm64) -> F4 (agg+gemm4) -> agg4 -> out.
// d_ws layout: rowptr[N+1] | dinv[N] | ssrc[E] | bufA[64N] | bufB[64N]
// Build temps alias into bufA (released before layer 0 writes bufA).
// ---------------------------------------------------------------------------

__device__ __forceinline__ float readlane_f(float v, int l) {
    union { float f; int i; } u;
    u.f = v;
    u.i = __builtin_amdgcn_readlane(u.i, l);
    return u.f;
}

// --- pass 1: coarse histogram of dst>>7 into NB buckets ---------------------
__global__ __launch_bounds__(256) void bucket_hist(const int* __restrict__ dst,
                                                   int* __restrict__ ghist,
                                                   int E, int NB) {
    __shared__ int h[1024];
    for (int i = threadIdx.x; i < NB; i += 256) h[i] = 0;
    __syncthreads();
    int i = blockIdx.x * blockDim.x + threadIdx.x;
    int stride = gridDim.x * blockDim.x;
    for (; i < E; i += stride) atomicAdd(&h[dst[i] >> 7], 1);
    __syncthreads();
    for (int j = threadIdx.x; j < NB; j += 256) {
        int c = h[j];
        if (c) atomicAdd(&ghist[j], c);
    }
}

// --- pass 2: exclusive scan of bucket counts (single block, 1024 thr) -------
__global__ void bucket_scan(const int* __restrict__ ghist, int* __restrict__ base,
                            int* __restrict__ cursor, int NB, int E) {
    int tid = threadIdx.x, lane = tid & 63, wid = tid >> 6;
    int v = (tid < NB) ? ghist[tid] : 0;
    int incl = v;
#pragma unroll
    for (int off = 1; off < 64; off <<= 1) {
        int t = __shfl_up(incl, off);
        if (lane >= off) incl += t;
    }
    __shared__ int ws[16];
    if (lane == 63) ws[wid] = incl;
    __syncthreads();
    if (tid == 0) {
        int run = 0;
        for (int i = 0; i < 16; ++i) { int t = ws[i]; ws[i] = run; run += t; }
    }
    __syncthreads();
    int excl = ws[wid] + incl - v;
    if (tid < NB) { base[tid] = excl; cursor[tid] = excl; }
    if (tid == 0) base[NB] = E;
}

// --- pass 3: scatter edges into bucket-sorted (bsrc, bdl) -------------------
__global__ __launch_bounds__(256) void bucket_scatter(
    const int* __restrict__ src, const int* __restrict__ dst,
    int* __restrict__ cursor, int* __restrict__ bsrc,
    unsigned char* __restrict__ bdl, int E, int NB) {
    __shared__ int h[1024];
    __shared__ int rb[1024];
    const int CH = 4096;
    for (int c0 = blockIdx.x * CH; c0 < E; c0 += gridDim.x * CH) {
        int cend = c0 + CH < E ? c0 + CH : E;
        for (int j = threadIdx.x; j < NB; j += 256) h[j] = 0;
        __syncthreads();
        for (int i = c0 + threadIdx.x; i < cend; i += 256)
            atomicAdd(&h[dst[i] >> 7], 1);
        __syncthreads();
        for (int j = threadIdx.x; j < NB; j += 256) {
            int c = h[j];
            rb[j] = c ? atomicAdd(&cursor[j], c) : 0;
            h[j] = 0;
        }
        __syncthreads();
        for (int i = c0 + threadIdx.x; i < cend; i += 256) {
            int d = dst[i];
            int b = d >> 7;
            int p = rb[b] + atomicAdd(&h[b], 1);
            bsrc[p] = src[i];
            bdl[p] = (unsigned char)(d & 127);
        }
        __syncthreads();
    }
}

// --- pass 4: per-bucket CSR finalize: rowptr, dinv, ssrc --------------------
__global__ __launch_bounds__(256) void bucket_finalize(
    const int* __restrict__ base, const int* __restrict__ bsrc,
    const unsigned char* __restrict__ bdl, int* __restrict__ rowptr,
    int* __restrict__ ssrc, float* __restrict__ dinv, int N, int NB, int E) {
    __shared__ int cnt[128];
    __shared__ int cur[128];
    __shared__ int w0sum;
    const int tid = threadIdx.x;
    const int lane = tid & 63;
    for (int b = blockIdx.x; b < NB; b += gridDim.x) {
        const int s = base[b], e = base[b + 1];
        const int d0 = b << 7;
        const int w = (N - d0 < 128) ? (N - d0) : 128;
        if (tid < 128) cnt[tid] = 0;
        __syncthreads();
        for (int i = s + tid; i < e; i += 256) atomicAdd(&cnt[bdl[i]], 1);
        __syncthreads();
        int v = (tid < 128) ? cnt[tid] : 0;
        int incl = v;
#pragma unroll
        for (int off = 1; off < 64; off <<= 1) {
            int t = __shfl_up(incl, off);
            if (lane >= off) incl += t;
        }
        if (tid == 63) w0sum = incl;
        __syncthreads();
        int excl = incl - v + ((tid >= 64 && tid < 128) ? w0sum : 0);
        if (tid < 128) cur[tid] = s + excl;
        if (tid < w) {
            rowptr[d0 + tid] = s + excl;
            dinv[d0 + tid] = rsqrtf((float)(v + 1));   // +1 self loop
        }
        __syncthreads();
        for (int i = s + tid; i < e; i += 256) {
            int p = atomicAdd(&cur[bdl[i]], 1);
            ssrc[p] = bsrc[i];
        }
        __syncthreads();
    }
    if (blockIdx.x == 0 && tid == 0) rowptr[N] = E;
}

// --- layer-0 dense transform + dinv pre-scale (row-major x[N,128]):
//   hs0[row,l] = dinv[row] * sum_k x[row,k] * W0[k,l]
__global__ __launch_bounds__(256) void gemm0_hs(
    const float* __restrict__ in, const float* __restrict__ W,
    const float* __restrict__ dinv, float* __restrict__ hs, int n) {
    const int lane = threadIdx.x & 63;
    const int gw = blockIdx.x * (blockDim.x >> 6) + (threadIdx.x >> 6);
    const int nw = gridDim.x * (blockDim.x >> 6);

    float wreg[128];
#pragma unroll
    for (int k = 0; k < 128; ++k) wreg[k] = W[k * 64 + lane];

    for (int row = gw; row < n; row += nw) {
        float xv0 = in[(size_t)row * 128 + lane];
        float xv1 = in[(size_t)row * 128 + 64 + lane];
        float a0 = 0.f, a1 = 0.f, a2 = 0.f, a3 = 0.f;
#pragma unroll
        for (int k = 0; k < 64; k += 4) {
            a0 = fmaf(readlane_f(xv0, k + 0), wreg[k + 0], a0);
            a1 = fmaf(readlane_f(xv0, k + 1), wreg[k + 1], a1);
            a2 = fmaf(readlane_f(xv0, k + 2), wreg[k + 2], a2);
            a3 = fmaf(readlane_f(xv0, k + 3), wreg[k + 3], a3);
        }
#pragma unroll
        for (int k = 0; k < 64; k += 4) {
            a0 = fmaf(readlane_f(xv1, k + 0), wreg[64 + k + 0], a0);
            a1 = fmaf(readlane_f(xv1, k + 1), wreg[64 + k + 1], a1);
            a2 = fmaf(readlane_f(xv1, k + 2), wreg[64 + k + 2], a2);
            a3 = fmaf(readlane_f(xv1, k + 3), wreg[64 + k + 3], a3);
        }
        float acc = (a0 + a1) + (a2 + a3);
        hs[(size_t)row * 64 + lane] = dinv[row] * acc;
    }
}

// --- fused: y = b + dinv*(self + gather-sum) ; hs_next = dinv * (lrelu(y)@W)
// wave = dst row (edge-balanced contiguous ranges), lane = feature.
__global__ __launch_bounds__(256) void agg_gemm64(
    const float* __restrict__ hs, const int* __restrict__ rowptr,
    const int* __restrict__ ssrc, const float* __restrict__ dinv,
    const float* __restrict__ b, const float* __restrict__ W,
    float* __restrict__ hs_next, int N, int E, int nwaves) {
    const int lane = threadIdx.x & 63;
    const int w = blockIdx.x * (blockDim.x >> 6) + (threadIdx.x >> 6);
    if (w >= nwaves) return;
    const float bl = b[lane];

    float wreg[64];
#pragma unroll
    for (int k = 0; k < 64; ++k) wreg[k] = W[k * 64 + lane];

    // first row r with rowptr[r] >= t
    auto lb = [&](long long t) {
        int lo = 0, hi = N;
        while (lo < hi) {
            int m = (lo + hi) >> 1;
            if ((long long)rowptr[m] < t) lo = m + 1; else hi = m;
        }
        return lo;
    };
    const long long q0 = (long long)w * E / nwaves;
    const long long q1 = (long long)(w + 1) * E / nwaves;
    int r0 = lb(q0);
    int r1 = (w == nwaves - 1) ? N : lb(q1);

    for (int d = r0; d < r1; ++d) {
        int e = __builtin_amdgcn_readfirstlane(rowptr[d]);
        const int end = __builtin_amdgcn_readfirstlane(rowptr[d + 1]);
        float acc0 = hs[(size_t)d * 64 + lane];   // self loop (pre-scaled)
        float acc1 = 0.f;
        for (; e + 8 <= end; e += 8) {
            int s0 = __builtin_nontemporal_load(ssrc + e + 0);
            int s1 = __builtin_nontemporal_load(ssrc + e + 1);
            int s2 = __builtin_nontemporal_load(ssrc + e + 2);
            int s3 = __builtin_nontemporal_load(ssrc + e + 3);
            int s4 = __builtin_nontemporal_load(ssrc + e + 4);
            int s5 = __builtin_nontemporal_load(ssrc + e + 5);
            int s6 = __builtin_nontemporal_load(ssrc + e + 6);
            int s7 = __builtin_nontemporal_load(ssrc + e + 7);
            float v0 = hs[(size_t)s0 * 64 + lane];
            float v1 = hs[(size_t)s1 * 64 + lane];
            float v2 = hs[(size_t)s2 * 64 + lane];
            float v3 = hs[(size_t)s3 * 64 + lane];
            float v4 = hs[(size_t)s4 * 64 + lane];
            float v5 = hs[(size_t)s5 * 64 + lane];
            float v6 = hs[(size_t)s6 * 64 + lane];
            float v7 = hs[(size_t)s7 * 64 + lane];
            acc0 += v0 + v2;
            acc1 += v1 + v3;
            acc0 += v4 + v6;
            acc1 += v5 + v7;
        }
        for (; e < end; ++e) {
            int s = __builtin_nontemporal_load(ssrc + e);
            acc0 += hs[(size_t)s * 64 + lane];
        }
        const float di = dinv[d];
        float y = fmaf(di, acc0 + acc1, bl);
        float xv = y >= 0.f ? y : 0.2f * y;       // leaky relu
        // next-layer transform: all 64 features of this row live across lanes
        float a0 = 0.f, a1 = 0.f, a2 = 0.f, a3 = 0.f;
#pragma unroll
        for (int k = 0; k < 64; k += 4) {
            a0 = fmaf(readlane_f(xv, k + 0), wreg[k + 0], a0);
            a1 = fmaf(readlane_f(xv, k + 1), wreg[k + 1], a1);
            a2 = fmaf(readlane_f(xv, k + 2), wreg[k + 2], a2);
            a3 = fmaf(readlane_f(xv, k + 3), wreg[k + 3], a3);
        }
        float h = (a0 + a1) + (a2 + a3);
        hs_next[(size_t)d * 64 + lane] = di * h;
    }
}

// --- fused final transform: y4 = agg(hs4)+b4 ; hs5 = dinv * (lrelu(y4)@W5) --
__global__ __launch_bounds__(256) void agg_gemm4(
    const float* __restrict__ hs, const int* __restrict__ rowptr,
    const int* __restrict__ ssrc, const float* __restrict__ dinv,
    const float* __restrict__ b, const float* __restrict__ W,  // [64,4]
    float* __restrict__ hs4, int N, int E, int nwaves) {
    const int lane = threadIdx.x & 63;
    const int w = blockIdx.x * (blockDim.x >> 6) + (threadIdx.x >> 6);
    if (w >= nwaves) return;
    const float bl = b[lane];
    const float4 w4 = *(const float4*)(W + lane * 4);

    auto lb = [&](long long t) {
        int lo = 0, hi = N;
        while (lo < hi) {
            int m = (lo + hi) >> 1;
            if ((long long)rowptr[m] < t) lo = m + 1; else hi = m;
        }
        return lo;
    };
    const long long q0 = (long long)w * E / nwaves;
    const long long q1 = (long long)(w + 1) * E / nwaves;
    int r0 = lb(q0);
    int r1 = (w == nwaves - 1) ? N : lb(q1);

    for (int d = r0; d < r1; ++d) {
        int e = __builtin_amdgcn_readfirstlane(rowptr[d]);
        const int end = __builtin_amdgcn_readfirstlane(rowptr[d + 1]);
        float acc0 = hs[(size_t)d * 64 + lane];
        float acc1 = 0.f;
        for (; e + 8 <= end; e += 8) {
            int s0 = __builtin_nontemporal_load(ssrc + e + 0);
            int s1 = __builtin_nontemporal_load(ssrc + e + 1);
            int s2 = __builtin_nontemporal_load(ssrc + e + 2);
            int s3 = __builtin_nontemporal_load(ssrc + e + 3);
            int s4 = __builtin_nontemporal_load(ssrc + e + 4);
            int s5 = __builtin_nontemporal_load(ssrc + e + 5);
            int s6 = __builtin_nontemporal_load(ssrc + e + 6);
            int s7 = __builtin_nontemporal_load(ssrc + e + 7);
            float v0 = hs[(size_t)s0 * 64 + lane];
            float v1 = hs[(size_t)s1 * 64 + lane];
            float v2 = hs[(size_t)s2 * 64 + lane];
            float v3 = hs[(size_t)s3 * 64 + lane];
            float v4 = hs[(size_t)s4 * 64 + lane];
            float v5 = hs[(size_t)s5 * 64 + lane];
            float v6 = hs[(size_t)s6 * 64 + lane];
            float v7 = hs[(size_t)s7 * 64 + lane];
            acc0 += v0 + v2;
            acc1 += v1 + v3;
            acc0 += v4 + v6;
            acc1 += v5 + v7;
        }
        for (; e < end; ++e) {
            int s = __builtin_nontemporal_load(ssrc + e);
            acc0 += hs[(size_t)s * 64 + lane];
        }
        const float di = dinv[d];
        float y = fmaf(di, acc0 + acc1, bl);
        float xv = y >= 0.f ? y : 0.2f * y;
        float p0 = xv * w4.x, p1 = xv * w4.y, p2 = xv * w4.z, p3 = xv * w4.w;
#pragma unroll
        for (int off = 1; off < 64; off <<= 1) {
            p0 += __shfl_xor(p0, off);
            p1 += __shfl_xor(p1, off);
            p2 += __shfl_xor(p2, off);
            p3 += __shfl_xor(p3, off);
        }
        if (lane == 0)
            ((float4*)hs4)[d] = make_float4(di * p0, di * p1, di * p2, di * p3);
    }
}

// --- final aggregation over pre-scaled hs4: out = b + dinv[d]*(self + sum) --
__global__ __launch_bounds__(256) void csr_agg4(
    const float* __restrict__ hs4, const int* __restrict__ rowptr,
    const int* __restrict__ ssrc, const float* __restrict__ dinv,
    const float* __restrict__ b, float* __restrict__ out, int n) {
    int i = blockIdx.x * blockDim.x + threadIdx.x;
    int stride = gridDim.x * blockDim.x;
    float b0 = b[0], b1 = b[1], b2 = b[2], b3 = b[3];
    for (; i < n; i += stride) {
        float4 hv = ((const float4*)hs4)[i];
        float a0 = hv.x, a1 = hv.y, a2 = hv.z, a3 = hv.w;   // self loop
        int e = rowptr[i], end = rowptr[i + 1];
        for (; e < end; ++e) {
            int s = ssrc[e];
            float4 v = ((const float4*)hs4)[s];
            a0 += v.x; a1 += v.y; a2 += v.z; a3 += v.w;
        }
        float di = dinv[i];
        ((float4*)out)[i] = make_float4(fmaf(di, a0, b0), fmaf(di, a1, b1),
                                        fmaf(di, a2, b2), fmaf(di, a3, b3));
    }
}

static inline size_t al64(size_t x) { return (x + 63) & ~(size_t)63; }

extern "C" void kernel_launch(void* const* d_in, const int* in_sizes, int n_in,
                              void* d_out, int out_size, void* d_ws, size_t ws_size,
                              hipStream_t stream) {
    const float* x  = (const float*)d_in[0];
    const int* ei   = (const int*)d_in[1];
    const float* W0 = (const float*)d_in[2];
    const float* b0 = (const float*)d_in[3];
    const float* W1 = (const float*)d_in[4];
    const float* b1 = (const float*)d_in[5];
    const float* W2 = (const float*)d_in[6];
    const float* b2 = (const float*)d_in[7];
    const float* W3 = (const float*)d_in[8];
    const float* b3 = (const float*)d_in[9];
    const float* W4 = (const float*)d_in[10];
    const float* b4 = (const float*)d_in[11];
    const float* W5 = (const float*)d_in[12];
    const float* b5 = (const float*)d_in[13];

    const int N = in_sizes[0] / 128;
    const int E = in_sizes[1] / 2;
    const int* src  = ei;       // edge_index[0] = message sources
    const int* dstp = ei + E;   // edge_index[1] = aggregation targets
    const int NB = (N + 127) >> 7;   // dst buckets of 128 ids (NB <= 1024)

    float* ws = (float*)d_ws;
    size_t off = 0;
    int*   rowptr = (int*)(ws + off);   off += al64((size_t)N + 1);
    float* dinv   = ws + off;           off += al64((size_t)N);
    int*   ssrc   = (int*)(ws + off);   off += al64((size_t)E);
    float* bufA   = ws + off;           off += (size_t)64 * N;
    float* bufB   = ws + off;

    // build temps alias into bufA (released before layer 0 writes bufA)
    int* ghist = (int*)bufA;                       // [1024]
    int* bbase = ghist + 1024;                     // [NB+1]
    int* bcur  = bbase + 1088;                     // [NB]
    int* bsrc  = (int*)(bufA + 4096);              // [E]
    unsigned char* bdl = (unsigned char*)(bsrc + E);  // [E]

    // ---- graph build (bucketed counting sort) ----
    hipMemsetAsync(ghist, 0, 1024 * sizeof(int), stream);
    bucket_hist<<<391, 256, 0, stream>>>(dstp, ghist, E, NB);
    bucket_scan<<<1, 1024, 0, stream>>>(ghist, bbase, bcur, NB, E);
    bucket_scatter<<<391, 256, 0, stream>>>(src, dstp, bcur, bsrc, bdl, E, NB);
    bucket_finalize<<<NB, 256, 0, stream>>>(bbase, bsrc, bdl, rowptr, ssrc, dinv, N, NB, E);

    const int AGG_BLOCKS = 2048;
    const int NWAVES = AGG_BLOCKS * 4;

    // ---- layer 0 dense: x[N,128] -> hs0 ----
    gemm0_hs<<<2048, 256, 0, stream>>>(x, W0, dinv, bufA, N);

    // ---- fused agg+gemm chain: F0..F3 ----
    agg_gemm64<<<AGG_BLOCKS, 256, 0, stream>>>(bufA, rowptr, ssrc, dinv, b0, W1, bufB, N, E, NWAVES);
    agg_gemm64<<<AGG_BLOCKS, 256, 0, stream>>>(bufB, rowptr, ssrc, dinv, b1, W2, bufA, N, E, NWAVES);
    agg_gemm64<<<AGG_BLOCKS, 256, 0, stream>>>(bufA, rowptr, ssrc, dinv, b2, W3, bufB, N, E, NWAVES);
    agg_gemm64<<<AGG_BLOCKS, 256, 0, stream>>>(bufB, rowptr, ssrc, dinv, b3, W4, bufA, N, E, NWAVES);

    // ---- F4: agg + final 64->4 transform -> hs5 in bufB ----
    agg_gemm4<<<AGG_BLOCKS, 256, 0, stream>>>(bufA, rowptr, ssrc, dinv, b4, W5, bufB, N, E, NWAVES);

    // ---- final aggregation -> out ----
    csr_agg4<<<1024, 256, 0, stream>>>(bufB, rowptr, ssrc, dinv, b5, (float*)d_out, N);
}